// Round 2
// baseline (436.088 us; speedup 1.0000x reference)
//
#include <hip/hip_runtime.h>
#include <hip/hip_bf16.h>
#include <cstdint>

#define Bb 2
#define Nc 6
#define Qn 900
#define Cc 256
#define Hc 116
#define Wc 200
#define HWp (Hc * Wc)          // 23200
#define PT 32
#define PTILES (HWp / PT)      // 725 (exact)
#define EPSf 1e-5f

__device__ __forceinline__ unsigned short f2bf(float f) {
    uint32_t u = __float_as_uint(f);
    uint32_t r = (u + 0x7FFFu + ((u >> 16) & 1u)) >> 16;   // round-to-nearest-even
    return (unsigned short)r;
}
__device__ __forceinline__ float bf2f(unsigned short h) {
    return __uint_as_float(((uint32_t)h) << 16);
}

// ---------------- Kernel T: (BN, C, H*W) fp32 -> (BN, H*W, C) bf16 ----------------
// Tile: PT=32 pixels x 256 channels. Reads float4 along pixels (coalesced, full
// line use), writes ushort4 along channels (512 B contiguous per wave).
__global__ void transpose_kernel(const float* __restrict__ in,
                                 unsigned short* __restrict__ out) {
    __shared__ float tile[PT][Cc + 1];   // +1 pad: write-phase banks conflict-free
    int blk = blockIdx.x;
    int bn  = blk / PTILES;
    int p0  = (blk % PTILES) * PT;
    int tid = threadIdx.x;

    const float* src = in + (size_t)bn * Cc * HWp + p0;
    int pq = tid & 7;     // which float4 within the 32-pixel tile
    int cb = tid >> 3;    // channel base 0..31
    #pragma unroll
    for (int k = 0; k < 8; ++k) {
        int c = cb + 32 * k;
        float4 v = *(const float4*)(src + (size_t)c * HWp + 4 * pq);
        tile[4 * pq + 0][c] = v.x;
        tile[4 * pq + 1][c] = v.y;
        tile[4 * pq + 2][c] = v.z;
        tile[4 * pq + 3][c] = v.w;
    }
    __syncthreads();

    int c4 = (tid & 63) * 4;
    int pw = tid >> 6;    // 0..3
    #pragma unroll
    for (int j = 0; j < 8; ++j) {
        int p = pw + 4 * j;
        ushort4 u;
        u.x = f2bf(tile[p][c4 + 0]);
        u.y = f2bf(tile[p][c4 + 1]);
        u.z = f2bf(tile[p][c4 + 2]);
        u.w = f2bf(tile[p][c4 + 3]);
        unsigned short* orow = out + ((size_t)bn * HWp + p0 + p) * Cc;
        *(ushort4*)(orow + c4) = u;
    }
}

// ---------------- Kernel S: fused projection + bilinear sample + masked mean ----------------
// block = one (b,q); thread = channel. Projection math is block-uniform (scalarized);
// corner reads are 512 B contiguous bf16 vectors (mostly L3-resident).
__global__ void sample_kernel(const unsigned short* __restrict__ trans, // (BN, HW, C) bf16
                              const float* __restrict__ ref_pts,        // (B, Q, 3)
                              const float* __restrict__ l2i,            // (B, N, 4, 4)
                              float* __restrict__ agg) {                // (B*Q, C)
    int bq = blockIdx.x;
    int b  = bq / Qn;
    int q  = bq % Qn;
    int c  = threadIdx.x;

    const float* p = ref_pts + ((size_t)b * Qn + q) * 3;
    float px = p[0], py = p[1], pz = p[2];

    float acc = 0.0f;
    for (int n = 0; n < Nc; ++n) {
        int bn = b * Nc + n;
        const float* M = l2i + (size_t)bn * 16;
        float h0 = M[0] * px + M[1] * py + M[2]  * pz + M[3];
        float h1 = M[4] * px + M[5] * py + M[6]  * pz + M[7];
        float h2 = M[8] * px + M[9] * py + M[10] * pz + M[11];

        float denom = fabsf(h2) + EPSf;
        float x2d = h0 / denom;
        float y2d = h1 / denom;
        float gx = x2d / (float)(Wc - 1) * 2.0f - 1.0f;
        float gy = y2d / (float)(Hc - 1) * 2.0f - 1.0f;
        bool front  = h2 > EPSf;
        bool in_img = fmaxf(fabsf(gx), fabsf(gy)) <= 1.0f;
        if (!(front && in_img)) continue;    // block-uniform branch

        float x = ((gx + 1.0f) * (float)Wc - 1.0f) * 0.5f;
        float y = ((gy + 1.0f) * (float)Hc - 1.0f) * 0.5f;
        float x0f = floorf(x), y0f = floorf(y);
        int x0 = (int)x0f, y0 = (int)y0f;
        int x1 = x0 + 1,  y1 = y0 + 1;
        float wx = x - x0f, wy = y - y0f;

        bool vx0 = (x0 >= 0) & (x0 < Wc);
        bool vx1 = (x1 >= 0) & (x1 < Wc);
        bool vy0 = (y0 >= 0) & (y0 < Hc);
        bool vy1 = (y1 >= 0) & (y1 < Hc);
        int cx0 = min(max(x0, 0), Wc - 1);
        int cx1 = min(max(x1, 0), Wc - 1);
        int cy0 = min(max(y0, 0), Hc - 1);
        int cy1 = min(max(y1, 0), Hc - 1);

        const unsigned short* base = trans + (size_t)bn * HWp * Cc;
        float v00 = bf2f(base[(size_t)(cy0 * Wc + cx0) * Cc + c]) * ((vx0 & vy0) ? 1.0f : 0.0f);
        float v01 = bf2f(base[(size_t)(cy0 * Wc + cx1) * Cc + c]) * ((vx1 & vy0) ? 1.0f : 0.0f);
        float v10 = bf2f(base[(size_t)(cy1 * Wc + cx0) * Cc + c]) * ((vx0 & vy1) ? 1.0f : 0.0f);
        float v11 = bf2f(base[(size_t)(cy1 * Wc + cx1) * Cc + c]) * ((vx1 & vy1) ? 1.0f : 0.0f);

        acc += (v00 * (1.0f - wx) + v01 * wx) * (1.0f - wy)
             + (v10 * (1.0f - wx) + v11 * wx) * wy;
    }
    agg[(size_t)bq * Cc + c] = acc * (1.0f / 6.0f);
}

// ---------------- Kernel C: out = agg @ W_out^T + b_out ----------------
#define QT 8
__global__ void out_gemm(const float* __restrict__ agg,    // (B*Q, C)
                         const float* __restrict__ Wm,     // (C, C)
                         const float* __restrict__ bias,   // (C,)
                         float* __restrict__ out) {        // (B*Q, C)
    __shared__ float sA[QT][Cc];
    int base_q = blockIdx.x * QT;
    int tid = threadIdx.x;

    for (int i = tid; i < QT * Cc; i += 256)
        sA[i / Cc][i % Cc] = agg[(size_t)base_q * Cc + i];
    __syncthreads();

    float acc[QT];
    #pragma unroll
    for (int j = 0; j < QT; ++j) acc[j] = 0.0f;

    const float4* wrow = (const float4*)(Wm + (size_t)tid * Cc);
    #pragma unroll 4
    for (int c4 = 0; c4 < Cc / 4; ++c4) {
        float4 w = wrow[c4];
        #pragma unroll
        for (int j = 0; j < QT; ++j) {
            acc[j] += w.x * sA[j][4 * c4 + 0] + w.y * sA[j][4 * c4 + 1]
                    + w.z * sA[j][4 * c4 + 2] + w.w * sA[j][4 * c4 + 3];
        }
    }
    float bb = bias[tid];
    #pragma unroll
    for (int j = 0; j < QT; ++j)
        out[(size_t)(base_q + j) * Cc + tid] = acc[j] + bb;
}

extern "C" void kernel_launch(void* const* d_in, const int* in_sizes, int n_in,
                              void* d_out, int out_size, void* d_ws, size_t ws_size,
                              hipStream_t stream) {
    // inputs: 0=query (unused), 1=reference_points, 2=image_features, 3=lidar2img, 4=W_out, 5=b_out
    const float* ref_pts = (const float*)d_in[1];
    const float* feats   = (const float*)d_in[2];
    const float* l2i     = (const float*)d_in[3];
    const float* Wm      = (const float*)d_in[4];
    const float* bias    = (const float*)d_in[5];
    float* out = (float*)d_out;

    size_t trans_bytes = (size_t)Bb * Nc * HWp * Cc * sizeof(unsigned short); // 142.5 MB
    unsigned short* trans = (unsigned short*)d_ws;
    float* agg = (float*)((char*)d_ws + trans_bytes);  // 142540800 is 256-aligned

    transpose_kernel<<<Bb * Nc * PTILES, 256, 0, stream>>>(feats, trans);
    sample_kernel<<<Bb * Qn, 256, 0, stream>>>(trans, ref_pts, l2i, agg);
    out_gemm<<<(Bb * Qn) / QT, 256, 0, stream>>>(agg, Wm, bias, out);
}